// Round 1
// baseline (642.044 us; speedup 1.0000x reference)
//
#include <hip/hip_runtime.h>

#define S 24
#define CIN 16
#define COUT 16
#define HALO (S + 2)                 // 26
#define TPAD 28                      // padded t-stride in LDS (8B-multiple rows)
#define NSTAGE (9 * HALO * HALO)     // 6084 elements per c_in tile

__global__ __launch_bounds__(256, 2)
void conv4d_kernel(const float* __restrict__ x,
                   const float* __restrict__ w,
                   const float* __restrict__ bias,
                   float* __restrict__ out) {
    // [p=kh*3+kw][dd 0..25][tt 0..25] with padded stride 28
    __shared__ __align__(16) float tile[9 * HALO * TPAD];
    __shared__ __align__(16) float wlds[COUT * 81];   // weights for current c_in

    const int blk = blockIdx.x;              // b*576 + h*24 + w
    const int b   = blk / (S * S);
    const int hw  = blk % (S * S);
    const int h   = hw / S;
    const int wq  = hw % S;

    const int tid   = threadIdx.x;
    const int c_out = tid >> 4;              // 0..15
    const int pos   = tid & 15;
    const int d0    = (pos >> 2) * 6;        // {0,6,12,18}
    const int t0    = (pos & 3) * 6;         // {0,6,12,18}

    float acc[6][6];
    const float bv = bias[c_out];
#pragma unroll
    for (int i = 0; i < 6; ++i)
#pragma unroll
        for (int j = 0; j < 6; ++j) acc[i][j] = bv;

    const int xb = b * (CIN * S * S * S * S);

    for (int ci = 0; ci < CIN; ++ci) {
        __syncthreads();   // protect LDS from previous iteration's readers
        const int cibase = xb + ci * (S * S * S * S);

        // ---- stage input halo tile (zeros = SAME padding) ----
        for (int k = 0; k < (NSTAGE + 255) / 256; ++k) {
            int idx = tid + k * 256;
            if (idx < NSTAGE) {
                int p  = idx / (HALO * HALO);
                int r  = idx % (HALO * HALO);
                int dd = r / HALO;
                int tt = r % HALO;
                int hh = h  + p / 3 - 1;
                int ww = wq + p % 3 - 1;
                int dp = dd - 1;
                int tp = tt - 1;
                float v = 0.0f;
                if ((unsigned)hh < S && (unsigned)ww < S &&
                    (unsigned)dp < S && (unsigned)tp < S) {
                    v = x[cibase + hh * (S * S * S) + ww * (S * S) + dp * S + tp];
                }
                tile[(p * HALO + dd) * TPAD + tt] = v;
            }
        }
        // ---- stage weights for this c_in: wlds[c*81 + r] ----
        for (int k = 0; k < 6; ++k) {
            int idx = tid + k * 256;
            if (idx < COUT * 81) {
                int c = idx / 81;
                int r = idx % 81;
                wlds[idx] = w[(c * CIN + ci) * 81 + r];
            }
        }
        __syncthreads();

        // ---- compute: 9 (kh,kw) taps, each a 3x3 (kd,kt) conv over (d,t) ----
        for (int p = 0; p < 9; ++p) {
            float wv[9];
#pragma unroll
            for (int j = 0; j < 9; ++j)
                wv[j] = wlds[c_out * 81 + p * 9 + j];

            float patch[8][8];
#pragma unroll
            for (int i = 0; i < 8; ++i) {
                const float2* row =
                    (const float2*)&tile[(p * HALO + d0 + i) * TPAD + t0];
#pragma unroll
                for (int j = 0; j < 4; ++j) {
                    float2 v = row[j];
                    patch[i][2 * j]     = v.x;
                    patch[i][2 * j + 1] = v.y;
                }
            }
#pragma unroll
            for (int i = 0; i < 6; ++i)
#pragma unroll
                for (int j = 0; j < 6; ++j) {
                    float s = acc[i][j];
#pragma unroll
                    for (int kd = 0; kd < 3; ++kd)
#pragma unroll
                        for (int kt = 0; kt < 3; ++kt)
                            s += patch[i + kd][j + kt] * wv[kd * 3 + kt];
                    acc[i][j] = s;
                }
        }
    }

    // ---- epilogue: write 6x6 tile ----
    const int obase = (b * COUT + c_out) * (S * S * S * S)
                    + h * (S * S * S) + wq * (S * S);
#pragma unroll
    for (int i = 0; i < 6; ++i)
#pragma unroll
        for (int j = 0; j < 6; ++j)
            out[obase + (d0 + i) * S + (t0 + j)] = acc[i][j];
}

extern "C" void kernel_launch(void* const* d_in, const int* in_sizes, int n_in,
                              void* d_out, int out_size, void* d_ws, size_t ws_size,
                              hipStream_t stream) {
    const float* x    = (const float*)d_in[0];
    const float* w    = (const float*)d_in[1];
    const float* bias = (const float*)d_in[2];
    float* out        = (float*)d_out;

    const int nblocks = 2 * S * S;   // b * h * w = 1152
    conv4d_kernel<<<nblocks, 256, 0, stream>>>(x, w, bias, out);
}

// Round 2
// 306.427 us; speedup vs baseline: 2.0953x; 2.0953x over previous
//
#include <hip/hip_runtime.h>

typedef __attribute__((ext_vector_type(8))) short bfrag;
typedef __attribute__((ext_vector_type(4))) float f32x4;

#define XS4 331776   // 24^4
#define XS3 13824    // 24^3
#define XS2 576      // 24^2

// ---------------- pre-kernel: split weights into bf16 hi/lo in ws ----------
// ws layout: u16 wsw[2][81][16 co][16 ci]  (hi half then lo half)
__global__ void wsplit_kernel(const float* __restrict__ w,
                              unsigned short* __restrict__ wsw) {
    int e = blockIdx.x * 256 + threadIdx.x;      // 0 .. 20735
    int tau = e % 81;
    int c2  = e / 81;                            // 0..255
    int co  = c2 >> 4, ci = c2 & 15;
    union { float f; unsigned u; } v;
    v.f = w[(co * 16 + ci) * 81 + tau];
    unsigned hi = v.u & 0xFFFF0000u;
    union { unsigned u; float f; } hv; hv.u = hi;
    union { float f; unsigned u; } rv; rv.f = v.f - hv.f;
    unsigned lo = rv.u & 0xFFFF0000u;
    int base = (tau * 16 + co) * 16 + ci;
    wsw[base]             = (unsigned short)(hi >> 16);
    wsw[1296 * 16 + base] = (unsigned short)(lo >> 16);
}

// ---------------- main kernel ----------------------------------------------
// block = (b, h, w, dseg(8), tseg(12)); 192 threads = 3 waves
// C tile per wave: 2 m-tiles (16 positions each) x 16 c_out
__global__ __launch_bounds__(192)
void conv4d_mfma(const float* __restrict__ x,
                 const unsigned short* __restrict__ wsw,
                 const float* __restrict__ bias,
                 float* __restrict__ out) {
    // x split: [2(hi/lo)][1260 sites = 9p*10dd*14tt][8 ci] bf16-bits
    __shared__ __align__(16) unsigned short xhl[2][1260][8];      // 40320 B
    // w split: [2(hi/lo)][81 tau][16 co][8 ci]
    __shared__ __align__(16) unsigned short whl[2][81][16][8];    // 41472 B
    __shared__ __align__(16) float zscr[4];                       // 16 B zeros

    const int tid = threadIdx.x;
    const int l   = tid & 63;

    int bid = blockIdx.x;
    const int b    = bid / 3456;
    int r          = bid % 3456;
    const int h    = r / 144;
    r              = r % 144;
    const int w0   = r / 6;
    const int seg  = r % 6;
    const int dseg = seg >> 1;          // 0..2
    const int tseg = seg & 1;           // 0..1
    const int dbase = dseg * 8, tbase = tseg * 12;

    if (tid < 4) zscr[tid] = 0.0f;

    // lane mappings
    const int i_  = l & 15;             // A-frag row (m index within tile)
    const int tl4 = l >> 4;             // A/B-frag k-group (tap within group)
    const int d_i = i_ >> 2;            // m -> (d,t) 4x4
    const int t_i = i_ & 3;
    const int co  = l & 15;             // B-frag col

    const int wv  = tid >> 6;
    const int mt0 = wv * 2, mt1 = wv * 2 + 1;     // this wave's m-tiles (0..5)
    const int dq0 = mt0 / 3, tq0 = mt0 % 3;
    const int dq1 = mt1 / 3, tq1 = mt1 % 3;
    const int mtoff0 = dq0 * 896 + tq0 * 64;      // (dq*4)*224B + (tq*4)*16B
    const int mtoff1 = dq1 * 896 + tq1 * 64;

    f32x4 acc0 = {0.f, 0.f, 0.f, 0.f};
    f32x4 acc1 = {0.f, 0.f, 0.f, 0.f};

    const char* xbase = (const char*)&xhl[0][0][0];
    const char* wbase = (const char*)&whl[0][0][0][0];
    const bfrag* zfrag = (const bfrag*)&zscr[0];

    for (int ch = 0; ch < 2; ++ch) {
        __syncthreads();   // protect LDS from previous chunk's readers

        // ---- stage weights: copy ci-slice [*,*,*, ch*8 .. ch*8+7] ----
        for (int k = 0; k < 14; ++k) {
            int idx = tid + k * 192;           // 0 .. 2591 (half*1296 + tau*16+co)
            if (idx < 2592) {
                uint4 v = *(const uint4*)((const char*)wsw + idx * 32 + ch * 16);
                *(uint4*)((char*)&whl[0][0][0][0] + idx * 16) = v;
            }
        }

        // ---- stage x: 1260 sites, 8 ci each, split into hi/lo bf16 ----
        for (int k = 0; k < 7; ++k) {
            int idx = tid + k * 192;
            if (idx < 1260) {
                int p  = idx / 140;
                int rr = idx - p * 140;
                int dd = rr / 14;
                int tt = rr - dd * 14;
                int hh = h  + p / 3 - 1;
                int ww = w0 + p % 3 - 1;
                int dp = dbase + dd - 1;
                int tp = tbase + tt - 1;
                unsigned hib[8], lob[8];
                bool valid = ((unsigned)hh < 24u) && ((unsigned)ww < 24u) &&
                             ((unsigned)dp < 24u) && ((unsigned)tp < 24u);
                if (valid) {
                    int g = b * (16 * XS4) + (ch * 8) * XS4
                          + hh * XS3 + ww * XS2 + dp * 24 + tp;
#pragma unroll
                    for (int c = 0; c < 8; ++c) {
                        union { float f; unsigned u; } v;
                        v.f = x[g + c * XS4];
                        unsigned hi = v.u & 0xFFFF0000u;
                        union { unsigned u; float f; } hv; hv.u = hi;
                        union { float f; unsigned u; } rv2; rv2.f = v.f - hv.f;
                        hib[c] = hi;
                        lob[c] = rv2.u & 0xFFFF0000u;
                    }
                } else {
#pragma unroll
                    for (int c = 0; c < 8; ++c) { hib[c] = 0u; lob[c] = 0u; }
                }
                uint4 ph, pl;
                ph.x = (hib[0] >> 16) | (hib[1] & 0xFFFF0000u);
                ph.y = (hib[2] >> 16) | (hib[3] & 0xFFFF0000u);
                ph.z = (hib[4] >> 16) | (hib[5] & 0xFFFF0000u);
                ph.w = (hib[6] >> 16) | (hib[7] & 0xFFFF0000u);
                pl.x = (lob[0] >> 16) | (lob[1] & 0xFFFF0000u);
                pl.y = (lob[2] >> 16) | (lob[3] & 0xFFFF0000u);
                pl.z = (lob[4] >> 16) | (lob[5] & 0xFFFF0000u);
                pl.w = (lob[6] >> 16) | (lob[7] & 0xFFFF0000u);
                *(uint4*)((char*)&xhl[0][0][0] + idx * 16)         = ph;
                *(uint4*)((char*)&xhl[0][0][0] + 20160 + idx * 16) = pl;
            }
        }
        __syncthreads();

        // ---- compute: 21 tap-groups (4 taps, taus 81..83 padded->zero) ----
        for (int g = 0; g < 21; ++g) {
            int tau = 4 * g + tl4;
            int p   = tau / 9;
            int r9  = tau - p * 9;
            int kd  = r9 / 3;
            int kt  = r9 - kd * 3;
            bool pad = (tau > 80);

            int woff = tau * 256 + co * 16;
            const bfrag* pwh = pad ? zfrag : (const bfrag*)(wbase + woff);
            const bfrag* pwl = pad ? zfrag : (const bfrag*)(wbase + woff + 20736);
            bfrag whf = *pwh;
            bfrag wlf = *pwl;

            int aoff = p * 2240 + (d_i + kd) * 224 + (t_i + kt) * 16;

            const bfrag* pxh0 = pad ? zfrag : (const bfrag*)(xbase + aoff + mtoff0);
            const bfrag* pxl0 = pad ? zfrag : (const bfrag*)(xbase + aoff + mtoff0 + 20160);
            bfrag xh0 = *pxh0;
            bfrag xl0 = *pxl0;
            const bfrag* pxh1 = pad ? zfrag : (const bfrag*)(xbase + aoff + mtoff1);
            const bfrag* pxl1 = pad ? zfrag : (const bfrag*)(xbase + aoff + mtoff1 + 20160);
            bfrag xh1 = *pxh1;
            bfrag xl1 = *pxl1;

            acc0 = __builtin_amdgcn_mfma_f32_16x16x32_bf16(xh0, whf, acc0, 0, 0, 0);
            acc1 = __builtin_amdgcn_mfma_f32_16x16x32_bf16(xh1, whf, acc1, 0, 0, 0);
            acc0 = __builtin_amdgcn_mfma_f32_16x16x32_bf16(xh0, wlf, acc0, 0, 0, 0);
            acc1 = __builtin_amdgcn_mfma_f32_16x16x32_bf16(xh1, wlf, acc1, 0, 0, 0);
            acc0 = __builtin_amdgcn_mfma_f32_16x16x32_bf16(xl0, whf, acc0, 0, 0, 0);
            acc1 = __builtin_amdgcn_mfma_f32_16x16x32_bf16(xl1, whf, acc1, 0, 0, 0);
        }
    }

    // ---- epilogue: D row i' = tl4*4 + r -> d=dq*4+tl4, t=tq*4+r ----
    const float bv = bias[co];
    const int ob = (b * 16 + co) * XS4 + h * XS3 + w0 * XS2;
    {
        int d = dbase + dq0 * 4 + tl4;
        int t = tbase + tq0 * 4;
        float4 v;
        v.x = acc0[0] + bv; v.y = acc0[1] + bv;
        v.z = acc0[2] + bv; v.w = acc0[3] + bv;
        *(float4*)&out[ob + d * 24 + t] = v;
    }
    {
        int d = dbase + dq1 * 4 + tl4;
        int t = tbase + tq1 * 4;
        float4 v;
        v.x = acc1[0] + bv; v.y = acc1[1] + bv;
        v.z = acc1[2] + bv; v.w = acc1[3] + bv;
        *(float4*)&out[ob + d * 24 + t] = v;
    }
}

extern "C" void kernel_launch(void* const* d_in, const int* in_sizes, int n_in,
                              void* d_out, int out_size, void* d_ws, size_t ws_size,
                              hipStream_t stream) {
    const float* x    = (const float*)d_in[0];
    const float* w    = (const float*)d_in[1];
    const float* bias = (const float*)d_in[2];
    float* out        = (float*)d_out;
    unsigned short* wsw = (unsigned short*)d_ws;   // needs 82944 B

    wsplit_kernel<<<81, 256, 0, stream>>>(w, wsw);
    conv4d_mfma<<<6912, 192, 0, stream>>>(x, wsw, bias, out);
}

// Round 3
// 243.089 us; speedup vs baseline: 2.6412x; 1.2606x over previous
//
#include <hip/hip_runtime.h>

typedef __attribute__((ext_vector_type(8))) short bfrag;
typedef __attribute__((ext_vector_type(4))) float f32x4;

#define XS4 331776   // 24^4
#define XS3 13824    // 24^3
#define XS2 576      // 24^2

// ---------------- pre-kernel: split weights into per-lane MFMA B-frag layout
// ws: u16 wfrag[cs=ch*2+s][tau 0..83][co 0..15][ci8 0..7]   (86016 B)
// cs: ch = ci-chunk (0..1), s = 0:hi 1:lo.  taus 81..83 are zero (pad).
__global__ void wsplit_kernel(const float* __restrict__ w,
                              unsigned int* __restrict__ wfrag) {
    int e = blockIdx.x * 256 + threadIdx.x;   // 0 .. 21503  (one u32 = 2 ci)
    int ci2 = e & 3;
    int co  = (e >> 2) & 15;
    int t84 = e >> 6;                          // cs*84 + tau
    int tau = t84 % 84;
    int cs  = t84 / 84;                        // 0..3
    int ch  = cs >> 1;
    int s   = cs & 1;

    unsigned int outv = 0u;
    if (tau < 81) {
        unsigned int half[2];
#pragma unroll
        for (int q = 0; q < 2; ++q) {
            int ci = ch * 8 + ci2 * 2 + q;
            union { float f; unsigned u; } v;
            v.f = w[(co * 16 + ci) * 81 + tau];
            unsigned hi = v.u & 0xFFFF0000u;
            union { unsigned u; float f; } hv; hv.u = hi;
            union { float f; unsigned u; } rv; rv.f = v.f - hv.f;
            unsigned lo = rv.u & 0xFFFF0000u;
            half[q] = (s == 0) ? hi : lo;
        }
        outv = (half[0] >> 16) | (half[1] & 0xFFFF0000u);
    }
    wfrag[e] = outv;
}

// ---------------- main kernel ----------------------------------------------
// block = (b, h, w, dseg(8), tseg(12)); 192 threads = 3 waves, 2 m-tiles/wave
__global__ __launch_bounds__(192, 3)
void conv4d_mfma(const float* __restrict__ x,
                 const unsigned short* __restrict__ wfrag,
                 const float* __restrict__ bias,
                 float* __restrict__ out) {
    // x split: [2(hi/lo)][1260 sites = 9p*10dd*14tt][8 ci] bf16-bits; 40320 B
    __shared__ __align__(16) unsigned short xhl[2][1260][8];

    const int tid = threadIdx.x;
    const int l   = tid & 63;

    int bid = blockIdx.x;
    const int b    = bid / 3456;
    int r          = bid % 3456;
    const int h    = r / 144;
    r              = r % 144;
    const int w0   = r / 6;
    const int seg  = r % 6;
    const int dseg = seg >> 1;          // 0..2
    const int tseg = seg & 1;           // 0..1
    const int dbase = dseg * 8, tbase = tseg * 12;

    // lane mappings
    const int i_  = l & 15;             // A-frag row (m index within tile)
    const int tl4 = l >> 4;             // k-group (tap within group of 4)
    const int d_i = i_ >> 2;            // m -> (d,t) 4x4
    const int t_i = i_ & 3;
    const int co  = l & 15;             // B-frag col (c_out)

    const int wv  = tid >> 6;
    const int mt0 = wv * 2, mt1 = wv * 2 + 1;     // m-tiles 0..5
    const int dq0 = mt0 / 3, tq0 = mt0 % 3;
    const int dq1 = mt1 / 3, tq1 = mt1 % 3;
    // per-lane A byte offsets (site*16B units: dd stride 224B, tt stride 16B)
    const int la0 = dq0 * 896 + tq0 * 64 + d_i * 224 + t_i * 16;
    const int la1 = dq1 * 896 + tq1 * 64 + d_i * 224 + t_i * 16;

    f32x4 acc0 = {0.f, 0.f, 0.f, 0.f};
    f32x4 acc1 = {0.f, 0.f, 0.f, 0.f};

    const char* xbase = (const char*)&xhl[0][0][0];
    const char* wB    = (const char*)wfrag + tl4 * 256 + co * 16;

    for (int ch = 0; ch < 2; ++ch) {
        __syncthreads();   // protect LDS from previous chunk's readers

        // ---- stage x: 1260 sites, 8 ci each, split into hi/lo bf16 ----
        for (int k = 0; k < 7; ++k) {
            int idx = tid + k * 192;
            if (idx < 1260) {
                int p  = idx / 140;
                int rr = idx - p * 140;
                int dd = rr / 14;
                int tt = rr - dd * 14;
                int hh = h  + p / 3 - 1;
                int ww = w0 + p % 3 - 1;
                int dp = dbase + dd - 1;
                int tp = tbase + tt - 1;
                unsigned hib[8], lob[8];
                bool valid = ((unsigned)hh < 24u) && ((unsigned)ww < 24u) &&
                             ((unsigned)dp < 24u) && ((unsigned)tp < 24u);
                if (valid) {
                    int g = b * (16 * XS4) + (ch * 8) * XS4
                          + hh * XS3 + ww * XS2 + dp * 24 + tp;
#pragma unroll
                    for (int c = 0; c < 8; ++c) {
                        union { float f; unsigned u; } v;
                        v.f = x[g + c * XS4];
                        unsigned hi = v.u & 0xFFFF0000u;
                        union { unsigned u; float f; } hv; hv.u = hi;
                        union { float f; unsigned u; } rv2; rv2.f = v.f - hv.f;
                        hib[c] = hi;
                        lob[c] = rv2.u & 0xFFFF0000u;
                    }
                } else {
#pragma unroll
                    for (int c = 0; c < 8; ++c) { hib[c] = 0u; lob[c] = 0u; }
                }
                uint4 ph, pl;
                ph.x = (hib[0] >> 16) | (hib[1] & 0xFFFF0000u);
                ph.y = (hib[2] >> 16) | (hib[3] & 0xFFFF0000u);
                ph.z = (hib[4] >> 16) | (hib[5] & 0xFFFF0000u);
                ph.w = (hib[6] >> 16) | (hib[7] & 0xFFFF0000u);
                pl.x = (lob[0] >> 16) | (lob[1] & 0xFFFF0000u);
                pl.y = (lob[2] >> 16) | (lob[3] & 0xFFFF0000u);
                pl.z = (lob[4] >> 16) | (lob[5] & 0xFFFF0000u);
                pl.w = (lob[6] >> 16) | (lob[7] & 0xFFFF0000u);
                *(uint4*)((char*)&xhl[0][0][0] + idx * 16)         = ph;
                *(uint4*)((char*)&xhl[0][0][0] + 20160 + idx * 16) = pl;
            }
        }
        __syncthreads();

        const char* pw = wB + ch * 43008;   // cs-major: ch*2*84*256

        // ---- compute: 21 tap-groups of 4; taus 81..83 have B==0 (pad) ----
#pragma unroll
        for (int g = 0; g < 21; ++g) {
            // B-frags straight from global (L2-hot, coalesced 1KB/wave)
            bfrag whf = *(const bfrag*)(pw + g * 1024);
            bfrag wlf = *(const bfrag*)(pw + g * 1024 + 21504);

            int tau  = 4 * g + tl4;
            int teff = tau > 80 ? 80 : tau;      // A clamp; B is 0 for pads
            int p    = teff / 9;
            int r9   = teff - p * 9;
            int kd   = r9 / 3;
            int kt   = r9 - kd * 3;
            int aoff = p * 2240 + kd * 224 + kt * 16;

            const char* ax = xbase + aoff;
            bfrag xh0 = *(const bfrag*)(ax + la0);
            bfrag xl0 = *(const bfrag*)(ax + la0 + 20160);
            bfrag xh1 = *(const bfrag*)(ax + la1);
            bfrag xl1 = *(const bfrag*)(ax + la1 + 20160);

            acc0 = __builtin_amdgcn_mfma_f32_16x16x32_bf16(xh0, whf, acc0, 0, 0, 0);
            acc1 = __builtin_amdgcn_mfma_f32_16x16x32_bf16(xh1, whf, acc1, 0, 0, 0);
            acc0 = __builtin_amdgcn_mfma_f32_16x16x32_bf16(xh0, wlf, acc0, 0, 0, 0);
            acc1 = __builtin_amdgcn_mfma_f32_16x16x32_bf16(xh1, wlf, acc1, 0, 0, 0);
            acc0 = __builtin_amdgcn_mfma_f32_16x16x32_bf16(xl0, whf, acc0, 0, 0, 0);
            acc1 = __builtin_amdgcn_mfma_f32_16x16x32_bf16(xl1, whf, acc1, 0, 0, 0);
        }
    }

    // ---- epilogue: D row i' = tl4*4 + r -> d=dq*4+tl4, t=tq*4+r ----
    const float bv = bias[co];
    const int ob = (b * 16 + co) * XS4 + h * XS3 + w0 * XS2;
    {
        int d = dbase + dq0 * 4 + tl4;
        int t = tbase + tq0 * 4;
        float4 v;
        v.x = acc0[0] + bv; v.y = acc0[1] + bv;
        v.z = acc0[2] + bv; v.w = acc0[3] + bv;
        *(float4*)&out[ob + d * 24 + t] = v;
    }
    {
        int d = dbase + dq1 * 4 + tl4;
        int t = tbase + tq1 * 4;
        float4 v;
        v.x = acc1[0] + bv; v.y = acc1[1] + bv;
        v.z = acc1[2] + bv; v.w = acc1[3] + bv;
        *(float4*)&out[ob + d * 24 + t] = v;
    }
}

extern "C" void kernel_launch(void* const* d_in, const int* in_sizes, int n_in,
                              void* d_out, int out_size, void* d_ws, size_t ws_size,
                              hipStream_t stream) {
    const float* x    = (const float*)d_in[0];
    const float* w    = (const float*)d_in[1];
    const float* bias = (const float*)d_in[2];
    float* out        = (float*)d_out;
    unsigned int* wsw = (unsigned int*)d_ws;   // needs 86016 B

    wsplit_kernel<<<84, 256, 0, stream>>>(w, wsw);
    conv4d_mfma<<<6912, 192, 0, stream>>>(x, (const unsigned short*)wsw, bias, out);
}

// Round 4
// 231.189 us; speedup vs baseline: 2.7771x; 1.0515x over previous
//
#include <hip/hip_runtime.h>

typedef __attribute__((ext_vector_type(8))) short bfrag;
typedef __attribute__((ext_vector_type(4))) float f32x4;

#define XS4 331776   // 24^4
#define XS3 13824    // 24^3
#define XS2 576      // 24^2

#define WS_ZERO   86016            // 64B zero scratch after wfrag
#define WS_XS     86080            // xsplit base (16B aligned)
#define XS_HALF_B 5308416          // XS4*16 bytes between hi and lo halves
#define WS_NEED   42553408ull      // 86080 + 4*2*XS4*16
#define NSITE     1260
#define NSITE_PAD 1280
#define LDS_LO    20480            // 1280*16

// ---------------- pre-kernel 1: weights -> per-lane MFMA B-frag layout ------
// wfrag: u16 [cs=ch*2+s][tau 0..83][co 0..15][ci8]; taus 81..83 zero.
// Also zeros the 64B zero-scratch (threads e<16 of block 0 land there).
__global__ void wsplit_kernel(const float* __restrict__ w,
                              unsigned int* __restrict__ ws) {
    int e = blockIdx.x * 256 + threadIdx.x;   // 0 .. 21503
    int ci2 = e & 3;
    int co  = (e >> 2) & 15;
    int t84 = e >> 6;
    int tau = t84 % 84;
    int cs  = t84 / 84;
    int ch  = cs >> 1;
    int s   = cs & 1;

    unsigned int outv = 0u;
    if (tau < 81) {
        unsigned int half[2];
#pragma unroll
        for (int q = 0; q < 2; ++q) {
            int ci = ch * 8 + ci2 * 2 + q;
            union { float f; unsigned u; } v;
            v.f = w[(co * 16 + ci) * 81 + tau];
            unsigned hi = v.u & 0xFFFF0000u;
            union { unsigned u; float f; } hv; hv.u = hi;
            union { float f; unsigned u; } rv; rv.f = v.f - hv.f;
            unsigned lo = rv.u & 0xFFFF0000u;
            half[q] = (s == 0) ? hi : lo;
        }
        outv = (half[0] >> 16) | (half[1] & 0xFFFF0000u);
    }
    ws[e] = outv;
    if (e < 16) ws[(WS_ZERO / 4) + e] = 0u;   // 64B zero scratch
}

// ---------------- pre-kernel 2: x -> split bf16 fragments -------------------
// xs: u16 [bc=b*2+ch][half][s4 = h*24^3+w*24^2+d*24+t][ci8]
__global__ void xsplit_kernel(const float* __restrict__ x,
                              unsigned short* __restrict__ xs) {
    int s4 = blockIdx.x * 256 + threadIdx.x;   // 0 .. 331775
    int bc = blockIdx.y;                        // b*2+ch
    const float* xp = x + (size_t)(bc * 8) * XS4 + s4;
    unsigned hib[8], lob[8];
#pragma unroll
    for (int c = 0; c < 8; ++c) {
        union { float f; unsigned u; } v;
        v.f = xp[(size_t)c * XS4];
        unsigned hi = v.u & 0xFFFF0000u;
        union { unsigned u; float f; } hv; hv.u = hi;
        union { float f; unsigned u; } rv; rv.f = v.f - hv.f;
        hib[c] = hi;
        lob[c] = rv.u & 0xFFFF0000u;
    }
    uint4 ph, pl;
    ph.x = (hib[0] >> 16) | (hib[1] & 0xFFFF0000u);
    ph.y = (hib[2] >> 16) | (hib[3] & 0xFFFF0000u);
    ph.z = (hib[4] >> 16) | (hib[5] & 0xFFFF0000u);
    ph.w = (hib[6] >> 16) | (hib[7] & 0xFFFF0000u);
    pl.x = (lob[0] >> 16) | (lob[1] & 0xFFFF0000u);
    pl.y = (lob[2] >> 16) | (lob[3] & 0xFFFF0000u);
    pl.z = (lob[4] >> 16) | (lob[5] & 0xFFFF0000u);
    pl.w = (lob[6] >> 16) | (lob[7] & 0xFFFF0000u);
    *(uint4*)(xs + ((size_t)(bc * 2 + 0) * XS4 + s4) * 8) = ph;
    *(uint4*)(xs + ((size_t)(bc * 2 + 1) * XS4 + s4) * 8) = pl;
}

// ---------------- main kernel v2: global_load_lds staging -------------------
__global__ __launch_bounds__(192, 3)
void conv4d_mfma_v2(const unsigned short* __restrict__ xs,
                    const unsigned short* __restrict__ wfrag,
                    const char* __restrict__ zptr,
                    const float* __restrict__ bias,
                    float* __restrict__ out) {
    __shared__ __align__(16) unsigned short xhl[2 * NSITE_PAD * 8];  // 40960 B

    const int tid  = threadIdx.x;
    const int l    = tid & 63;
    const int wv   = tid >> 6;

    int bid = blockIdx.x;
    const int b    = bid / 3456;
    int r          = bid % 3456;
    const int h    = r / 144;
    r              = r % 144;
    const int w0   = r / 6;
    const int seg  = r % 6;
    const int dbase = (seg >> 1) * 8, tbase = (seg & 1) * 12;

    const int i_  = l & 15;
    const int tl4 = l >> 4;
    const int d_i = i_ >> 2;
    const int t_i = i_ & 3;
    const int co  = l & 15;

    const int mt0 = wv * 2, mt1 = wv * 2 + 1;
    const int dq0 = mt0 / 3, tq0 = mt0 % 3;
    const int dq1 = mt1 / 3, tq1 = mt1 % 3;
    const int la0 = dq0 * 896 + tq0 * 64 + d_i * 224 + t_i * 16;
    const int la1 = dq1 * 896 + tq1 * 64 + d_i * 224 + t_i * 16;

    // hoisted per-lane tap offsets (fully unrolled -> registers)
    int aoffs[21];
#pragma unroll
    for (int g = 0; g < 21; ++g) {
        int tau  = 4 * g + tl4;
        int teff = tau > 80 ? 80 : tau;
        int p    = teff / 9;
        int r9   = teff - p * 9;
        int kd   = r9 / 3;
        int kt   = r9 - kd * 3;
        aoffs[g] = p * 2240 + kd * 224 + kt * 16;
    }

    f32x4 acc0 = {0.f, 0.f, 0.f, 0.f};
    f32x4 acc1 = {0.f, 0.f, 0.f, 0.f};

    const char* xbase = (const char*)&xhl[0];
    const char* xsb   = (const char*)xs;
    const char* wB    = (const char*)wfrag + tl4 * 256 + co * 16;

    for (int ch = 0; ch < 2; ++ch) {
        __syncthreads();

        const unsigned base16 = (unsigned)((b * 2 + ch) * 2) * (unsigned)(XS4 * 16);

        // ---- stage via direct global->LDS DMA, 16B per lane ----
        for (int k = 0; k < 7; ++k) {
            int idx0 = k * 192 + wv * 64;          // wave-uniform
            if (idx0 < NSITE_PAD) {
                int idx = idx0 + l;
                int p  = idx / 140;
                int rr = idx - p * 140;
                int dd = rr / 14;
                int tt = rr - dd * 14;
                int hh = h  + p / 3 - 1;
                int ww = w0 + p % 3 - 1;
                int dp = dbase + dd - 1;
                int tp = tbase + tt - 1;
                bool valid = ((unsigned)hh < 24u) && ((unsigned)ww < 24u) &&
                             ((unsigned)dp < 24u) && ((unsigned)tp < 24u) &&
                             (idx < NSITE);
                const char* gh = zptr;
                const char* gl = zptr;
                if (valid) {
                    unsigned off = base16 +
                        (unsigned)(hh * XS3 + ww * XS2 + dp * 24 + tp) * 16u;
                    gh = xsb + off;
                    gl = gh + XS_HALF_B;
                }
                char* lp = (char*)&xhl[0] + idx * 16;
                __builtin_amdgcn_global_load_lds(
                    (const __attribute__((address_space(1))) void*)gh,
                    (__attribute__((address_space(3))) void*)lp, 16, 0, 0);
                __builtin_amdgcn_global_load_lds(
                    (const __attribute__((address_space(1))) void*)gl,
                    (__attribute__((address_space(3))) void*)(lp + LDS_LO), 16, 0, 0);
            }
        }
        __syncthreads();

        const char* pw = wB + ch * 43008;

#pragma unroll
        for (int g = 0; g < 21; ++g) {
            bfrag whf = *(const bfrag*)(pw + g * 1024);
            bfrag wlf = *(const bfrag*)(pw + g * 1024 + 21504);

            const char* ax = xbase + aoffs[g];
            bfrag xh0 = *(const bfrag*)(ax + la0);
            bfrag xl0 = *(const bfrag*)(ax + la0 + LDS_LO);
            bfrag xh1 = *(const bfrag*)(ax + la1);
            bfrag xl1 = *(const bfrag*)(ax + la1 + LDS_LO);

            __builtin_amdgcn_s_setprio(1);
            acc0 = __builtin_amdgcn_mfma_f32_16x16x32_bf16(xh0, whf, acc0, 0, 0, 0);
            acc1 = __builtin_amdgcn_mfma_f32_16x16x32_bf16(xh1, whf, acc1, 0, 0, 0);
            acc0 = __builtin_amdgcn_mfma_f32_16x16x32_bf16(xh0, wlf, acc0, 0, 0, 0);
            acc1 = __builtin_amdgcn_mfma_f32_16x16x32_bf16(xh1, wlf, acc1, 0, 0, 0);
            acc0 = __builtin_amdgcn_mfma_f32_16x16x32_bf16(xl0, whf, acc0, 0, 0, 0);
            acc1 = __builtin_amdgcn_mfma_f32_16x16x32_bf16(xl1, whf, acc1, 0, 0, 0);
            __builtin_amdgcn_s_setprio(0);
        }
    }

    const float bv = bias[co];
    const int ob = (b * 16 + co) * XS4 + h * XS3 + w0 * XS2;
    {
        int d = dbase + dq0 * 4 + tl4;
        int t = tbase + tq0 * 4;
        float4 v;
        v.x = acc0[0] + bv; v.y = acc0[1] + bv;
        v.z = acc0[2] + bv; v.w = acc0[3] + bv;
        *(float4*)&out[ob + d * 24 + t] = v;
    }
    {
        int d = dbase + dq1 * 4 + tl4;
        int t = tbase + tq1 * 4;
        float4 v;
        v.x = acc1[0] + bv; v.y = acc1[1] + bv;
        v.z = acc1[2] + bv; v.w = acc1[3] + bv;
        *(float4*)&out[ob + d * 24 + t] = v;
    }
}

// ---------------- fallback (round-3 kernel, used if ws too small) -----------
__global__ __launch_bounds__(192, 3)
void conv4d_mfma_v1(const float* __restrict__ x,
                    const unsigned short* __restrict__ wfrag,
                    const float* __restrict__ bias,
                    float* __restrict__ out) {
    __shared__ __align__(16) unsigned short xhl[2][1260][8];

    const int tid = threadIdx.x;
    const int l   = tid & 63;

    int bid = blockIdx.x;
    const int b    = bid / 3456;
    int r          = bid % 3456;
    const int h    = r / 144;
    r              = r % 144;
    const int w0   = r / 6;
    const int seg  = r % 6;
    const int dbase = (seg >> 1) * 8, tbase = (seg & 1) * 12;

    const int i_  = l & 15;
    const int tl4 = l >> 4;
    const int d_i = i_ >> 2;
    const int t_i = i_ & 3;
    const int co  = l & 15;

    const int wv  = tid >> 6;
    const int mt0 = wv * 2, mt1 = wv * 2 + 1;
    const int dq0 = mt0 / 3, tq0 = mt0 % 3;
    const int dq1 = mt1 / 3, tq1 = mt1 % 3;
    const int la0 = dq0 * 896 + tq0 * 64 + d_i * 224 + t_i * 16;
    const int la1 = dq1 * 896 + tq1 * 64 + d_i * 224 + t_i * 16;

    f32x4 acc0 = {0.f, 0.f, 0.f, 0.f};
    f32x4 acc1 = {0.f, 0.f, 0.f, 0.f};

    const char* xbase = (const char*)&xhl[0][0][0];
    const char* wB    = (const char*)wfrag + tl4 * 256 + co * 16;

    for (int ch = 0; ch < 2; ++ch) {
        __syncthreads();
        for (int k = 0; k < 7; ++k) {
            int idx = tid + k * 192;
            if (idx < 1260) {
                int p  = idx / 140;
                int rr = idx - p * 140;
                int dd = rr / 14;
                int tt = rr - dd * 14;
                int hh = h  + p / 3 - 1;
                int ww = w0 + p % 3 - 1;
                int dp = dbase + dd - 1;
                int tp = tbase + tt - 1;
                unsigned hib[8], lob[8];
                bool valid = ((unsigned)hh < 24u) && ((unsigned)ww < 24u) &&
                             ((unsigned)dp < 24u) && ((unsigned)tp < 24u);
                if (valid) {
                    int g = b * (16 * XS4) + (ch * 8) * XS4
                          + hh * XS3 + ww * XS2 + dp * 24 + tp;
#pragma unroll
                    for (int c = 0; c < 8; ++c) {
                        union { float f; unsigned u; } v;
                        v.f = x[g + c * XS4];
                        unsigned hi = v.u & 0xFFFF0000u;
                        union { unsigned u; float f; } hv; hv.u = hi;
                        union { float f; unsigned u; } rv2; rv2.f = v.f - hv.f;
                        hib[c] = hi;
                        lob[c] = rv2.u & 0xFFFF0000u;
                    }
                } else {
#pragma unroll
                    for (int c = 0; c < 8; ++c) { hib[c] = 0u; lob[c] = 0u; }
                }
                uint4 ph, pl;
                ph.x = (hib[0] >> 16) | (hib[1] & 0xFFFF0000u);
                ph.y = (hib[2] >> 16) | (hib[3] & 0xFFFF0000u);
                ph.z = (hib[4] >> 16) | (hib[5] & 0xFFFF0000u);
                ph.w = (hib[6] >> 16) | (hib[7] & 0xFFFF0000u);
                pl.x = (lob[0] >> 16) | (lob[1] & 0xFFFF0000u);
                pl.y = (lob[2] >> 16) | (lob[3] & 0xFFFF0000u);
                pl.z = (lob[4] >> 16) | (lob[5] & 0xFFFF0000u);
                pl.w = (lob[6] >> 16) | (lob[7] & 0xFFFF0000u);
                *(uint4*)((char*)&xhl[0][0][0] + idx * 16)         = ph;
                *(uint4*)((char*)&xhl[0][0][0] + 20160 + idx * 16) = pl;
            }
        }
        __syncthreads();

        const char* pw = wB + ch * 43008;
#pragma unroll
        for (int g = 0; g < 21; ++g) {
            bfrag whf = *(const bfrag*)(pw + g * 1024);
            bfrag wlf = *(const bfrag*)(pw + g * 1024 + 21504);

            int tau  = 4 * g + tl4;
            int teff = tau > 80 ? 80 : tau;
            int p    = teff / 9;
            int r9   = teff - p * 9;
            int kd   = r9 / 3;
            int kt   = r9 - kd * 3;
            int aoff = p * 2240 + kd * 224 + kt * 16;

            const char* ax = xbase + aoff;
            bfrag xh0 = *(const bfrag*)(ax + la0);
            bfrag xl0 = *(const bfrag*)(ax + la0 + 20160);
            bfrag xh1 = *(const bfrag*)(ax + la1);
            bfrag xl1 = *(const bfrag*)(ax + la1 + 20160);

            acc0 = __builtin_amdgcn_mfma_f32_16x16x32_bf16(xh0, whf, acc0, 0, 0, 0);
            acc1 = __builtin_amdgcn_mfma_f32_16x16x32_bf16(xh1, whf, acc1, 0, 0, 0);
            acc0 = __builtin_amdgcn_mfma_f32_16x16x32_bf16(xh0, wlf, acc0, 0, 0, 0);
            acc1 = __builtin_amdgcn_mfma_f32_16x16x32_bf16(xh1, wlf, acc1, 0, 0, 0);
            acc0 = __builtin_amdgcn_mfma_f32_16x16x32_bf16(xl0, whf, acc0, 0, 0, 0);
            acc1 = __builtin_amdgcn_mfma_f32_16x16x32_bf16(xl1, whf, acc1, 0, 0, 0);
        }
    }

    const float bv = bias[co];
    const int ob = (b * 16 + co) * XS4 + h * XS3 + w0 * XS2;
    {
        int d = dbase + dq0 * 4 + tl4;
        int t = tbase + tq0 * 4;
        float4 v;
        v.x = acc0[0] + bv; v.y = acc0[1] + bv;
        v.z = acc0[2] + bv; v.w = acc0[3] + bv;
        *(float4*)&out[ob + d * 24 + t] = v;
    }
    {
        int d = dbase + dq1 * 4 + tl4;
        int t = tbase + tq1 * 4;
        float4 v;
        v.x = acc1[0] + bv; v.y = acc1[1] + bv;
        v.z = acc1[2] + bv; v.w = acc1[3] + bv;
        *(float4*)&out[ob + d * 24 + t] = v;
    }
}

extern "C" void kernel_launch(void* const* d_in, const int* in_sizes, int n_in,
                              void* d_out, int out_size, void* d_ws, size_t ws_size,
                              hipStream_t stream) {
    const float* x    = (const float*)d_in[0];
    const float* w    = (const float*)d_in[1];
    const float* bias = (const float*)d_in[2];
    float* out        = (float*)d_out;
    char* ws          = (char*)d_ws;
    unsigned* wfrag   = (unsigned*)ws;

    wsplit_kernel<<<84, 256, 0, stream>>>(w, wfrag);

    if (ws_size >= WS_NEED) {
        unsigned short* xs = (unsigned short*)(ws + WS_XS);
        xsplit_kernel<<<dim3(1296, 4), 256, 0, stream>>>(x, xs);
        conv4d_mfma_v2<<<6912, 192, 0, stream>>>(
            xs, (const unsigned short*)wfrag, ws + WS_ZERO, bias, out);
    } else {
        conv4d_mfma_v1<<<6912, 192, 0, stream>>>(
            x, (const unsigned short*)wfrag, bias, out);
    }
}